// Round 2
// baseline (5666.801 us; speedup 1.0000x reference)
//
#include <hip/hip_runtime.h>

#define NOBS 2048
#define NX   128
#define NY   64
#define BS   8            // scenarios per solver block
#define NT   1024         // solver block threads (16 waves)
#define NWAVE (NT / 64)
#define NITER 64

// ---- DPP wave reductions (VALU pipe, keeps LDS pipe free) ----
template <int CTRL>
__device__ __forceinline__ float dpp_f(float x) {
    return __int_as_float(__builtin_amdgcn_update_dpp(
        0, __float_as_int(x), CTRL, 0xf, 0xf, true));  // bound_ctrl: invalid lanes read 0
}
// After these, lane 63 holds the full-wave result.
__device__ __forceinline__ float wave_sum64(float v) {
    v += dpp_f<0x111>(v);   // row_shr:1
    v += dpp_f<0x112>(v);   // row_shr:2
    v += dpp_f<0x114>(v);   // row_shr:4
    v += dpp_f<0x118>(v);   // row_shr:8  -> lane 16r+15 = row sum
    v += dpp_f<0x142>(v);   // row_bcast15
    v += dpp_f<0x143>(v);   // row_bcast31 -> lane 63 = total
    return v;
}
__device__ __forceinline__ float wave_max64_nonneg(float v) {  // requires v >= 0
    v = fmaxf(v, dpp_f<0x111>(v));
    v = fmaxf(v, dpp_f<0x112>(v));
    v = fmaxf(v, dpp_f<0x114>(v));
    v = fmaxf(v, dpp_f<0x118>(v));
    v = fmaxf(v, dpp_f<0x142>(v));
    v = fmaxf(v, dpp_f<0x143>(v));
    return v;
}

// ---- Kernel 1: Y_hat = X@W^T + b ; ep = Y - Y_hat ; epsum = sum(ep) ----
__global__ __launch_bounds__(256) void prep_kernel(
    const float* __restrict__ X, const float* __restrict__ Y,
    const float* __restrict__ W, const float* __restrict__ b,
    float* __restrict__ yhat_out, float* __restrict__ ep, float* __restrict__ epsum)
{
    __shared__ float Xs[4][NX];
    const int t = threadIdx.x;
    const int row0 = blockIdx.x * 4;
    for (int f = t; f < 4 * NX; f += 256)
        Xs[f >> 7][f & 127] = X[(row0 + (f >> 7)) * NX + (f & 127)];
    __syncthreads();

    const int k = t & 63;
    const int r = t >> 6;
    const float4* W4 = reinterpret_cast<const float4*>(W + k * NX);
    const float4* X4 = reinterpret_cast<const float4*>(&Xs[r][0]);
    float acc = 0.f;
    #pragma unroll
    for (int x = 0; x < NX / 4; ++x) {
        float4 wv = W4[x];
        float4 xv = X4[x];
        acc += wv.x * xv.x + wv.y * xv.y + wv.z * xv.z + wv.w * xv.w;
    }
    const float yh = acc + b[k];
    const int i = row0 + r;
    yhat_out[i * NY + k] = yh;
    const float e = Y[i * NY + k] - yh;
    ep[i * NY + k] = e;

    float se = wave_sum64(e);
    if ((t & 63) == 63) atomicAdd(epsum, se);
}

// ---- Kernel 2: batched projected-subgradient DRO solve ----
__global__ __launch_bounds__(NT, 4) void solve_kernel(
    const float* __restrict__ ep, const float* __restrict__ yhat,
    const float* __restrict__ epsum, const float* __restrict__ rho_p,
    float* __restrict__ zout)
{
    __shared__ float V[NOBS][BS];           // 64 KB  weighted residual v = omega .* s
    __shared__ float Rpart[NWAVE][NY][BS];  // 32 KB  per-wave partial r
    __shared__ float Rr[NY][BS];            // 2 KB   r = ep^T v
    __shared__ float Zs[BS][NY];            // 2 KB   z for Phase A broadcast reads
    __shared__ float scal[32];              // [a | eq | a*s | eq*s] x 8 scenarios
    __shared__ int   umaxI[BS];             // float bits of umax (u >= 0)
    __shared__ float cS[BS], lamS[BS], gcS[BS], glamS[BS];

    const int t = threadIdx.x;
    const int lane = t & 63;
    const int wv = t >> 6;
    const int sc0 = blockIdx.x * BS;
    const float rho = rho_p[0];

    // persistent per-wave registers (waves 0..7 own scenario j = wv)
    float zReg = 1.0f / 64.0f;
    float yhReg = 0.0f;
    if (wv < BS) yhReg = yhat[(sc0 + wv) * NY + lane];

    if (t < BS * NY) Zs[t >> 6][t & 63] = 1.0f / 64.0f;
    if (t < 32) scal[t] = 0.0f;
    if (t < BS) {
        umaxI[t] = 0;
        cS[t] = epsum[0] * (1.0f / 131072.0f);  // mean(ep) == mean(ep @ z0)
        lamS[t] = 1.0f;
    }
    __syncthreads();

    const int i0 = t;          // Phase A/B4: thread owns obs rows t and t+1024
    const int i1 = t + NT;
    const float4* ep4 = reinterpret_cast<const float4*>(ep);
    const float4* epA = ep4 + i0 * (NY / 4);
    const float4* epB = ep4 + i1 * (NY / 4);

    for (int it = 0; it < NITER; ++it) {
        const float lr = 0.05f / sqrtf((float)it + 1.0f);

        // ---- Phase A: s = ep.z - c for 2 rows x 8 scenarios ----
        float s0[BS], s1[BS];
        #pragma unroll
        for (int j = 0; j < BS; ++j) { s0[j] = 0.f; s1[j] = 0.f; }
        #pragma unroll 4
        for (int k4 = 0; k4 < NY / 4; ++k4) {
            const float4 ea = epA[k4];
            const float4 eb = epB[k4];
            #pragma unroll
            for (int j = 0; j < BS; ++j) {
                const float4 zv = *reinterpret_cast<const float4*>(&Zs[j][k4 * 4]);
                s0[j] += ea.x * zv.x + ea.y * zv.y + ea.z * zv.z + ea.w * zv.w;
                s1[j] += eb.x * zv.x + eb.y * zv.y + eb.z * zv.z + eb.w * zv.w;
            }
        }
        float lamR[BS];
        #pragma unroll
        for (int j = 0; j < BS; ++j) {
            const float cj = cS[j];
            lamR[j] = lamS[j];
            s0[j] -= cj; s1[j] -= cj;
        }

        // ---- B1: umax per scenario via DPP max + LDS atomic max (bits, u>=0) ----
        #pragma unroll
        for (int j = 0; j < BS; ++j) {
            float pm = fmaxf(s0[j] * s0[j], s1[j] * s1[j]);
            pm = wave_max64_nonneg(pm);
            if (lane == 63) atomicMax(&umaxI[j], __float_as_int(pm));
        }
        __syncthreads();                                   // bar 1

        float um[BS];
        #pragma unroll
        for (int j = 0; j < BS; ++j) um[j] = __int_as_float(umaxI[j]);

        // ---- B2: sums of a, eq, a*s, eq*s (JAX balanced-tie semantics) ----
        #pragma unroll
        for (int j = 0; j < BS; ++j) {
            const float umj = um[j], lm = lamR[j];
            float pa, pe, pas, pes;
            {
                const float s = s0[j], u = s * s;
                const float x = (u - umj) + lm;
                const float a = (x > -lm) ? 1.0f : ((x == -lm) ? 0.5f : 0.0f);
                const float e = (u == umj) ? 1.0f : 0.0f;
                pa = a; pe = e; pas = a * s; pes = e * s;
            }
            {
                const float s = s1[j], u = s * s;
                const float x = (u - umj) + lm;
                const float a = (x > -lm) ? 1.0f : ((x == -lm) ? 0.5f : 0.0f);
                const float e = (u == umj) ? 1.0f : 0.0f;
                pa += a; pe += e; pas += a * s; pes += e * s;
            }
            pa = wave_sum64(pa); pe = wave_sum64(pe);
            pas = wave_sum64(pas); pes = wave_sum64(pes);
            if (lane == 63) {
                atomicAdd(&scal[j], pa);       atomicAdd(&scal[8 + j], pe);
                atomicAdd(&scal[16 + j], pas); atomicAdd(&scal[24 + j], pes);
            }
        }
        __syncthreads();                                   // bar 2

        // ---- B4: wA inline per thread; v = (a/n + eq*wA) * s into V ----
        float wA[BS];
        #pragma unroll
        for (int j = 0; j < BS; ++j) {
            const float abar = scal[j] * (1.0f / (float)NOBS);
            wA[j] = (1.0f - abar) / scal[8 + j];
        }
        if (t < BS) {   // finalize gc/glam while others build v
            const float abar = scal[t] * (1.0f / (float)NOBS);
            const float wAt = (1.0f - abar) / scal[8 + t];
            gcS[t] = -2.0f * (scal[16 + t] * (1.0f / (float)NOBS) + wAt * scal[24 + t]);
            glamS[t] = (rho - 2.0f) + 2.0f * abar;
        }
        {
            float v0[BS], v1[BS];
            #pragma unroll
            for (int j = 0; j < BS; ++j) {
                const float umj = um[j], lm = lamR[j], wAj = wA[j];
                {
                    const float s = s0[j], u = s * s;
                    const float x = (u - umj) + lm;
                    const float a = (x > -lm) ? 1.0f : ((x == -lm) ? 0.5f : 0.0f);
                    const float e = (u == umj) ? 1.0f : 0.0f;
                    v0[j] = (a * (1.0f / (float)NOBS) + e * wAj) * s;
                }
                {
                    const float s = s1[j], u = s * s;
                    const float x = (u - umj) + lm;
                    const float a = (x > -lm) ? 1.0f : ((x == -lm) ? 0.5f : 0.0f);
                    const float e = (u == umj) ? 1.0f : 0.0f;
                    v1[j] = (a * (1.0f / (float)NOBS) + e * wAj) * s;
                }
            }
            *reinterpret_cast<float4*>(&V[i0][0]) = make_float4(v0[0], v0[1], v0[2], v0[3]);
            *reinterpret_cast<float4*>(&V[i0][4]) = make_float4(v0[4], v0[5], v0[6], v0[7]);
            *reinterpret_cast<float4*>(&V[i1][0]) = make_float4(v1[0], v1[1], v1[2], v1[3]);
            *reinterpret_cast<float4*>(&V[i1][4]) = make_float4(v1[4], v1[5], v1[6], v1[7]);
        }
        __syncthreads();                                   // bar 3

        // ---- Phase C: r = ep^T v, 4 rows per step, sub-split lanes ----
        {
            const int sub = lane >> 4;        // 0..3: row within quad
            const int kq  = lane & 15;        // k-quad: k = 4*kq + c
            float rp0[BS], rp1[BS], rp2[BS], rp3[BS];
            #pragma unroll
            for (int j = 0; j < BS; ++j) { rp0[j] = 0.f; rp1[j] = 0.f; rp2[j] = 0.f; rp3[j] = 0.f; }

            const int rbase = wv * (NOBS / NWAVE) + sub;   // rows rbase + 4*ii
            const float4* vp = reinterpret_cast<const float4*>(&V[rbase][0]);
            #pragma unroll
            for (int c8 = 0; c8 < 8; ++c8) {
                const float4* epc = ep4 + (rbase + c8 * 16) * (NY / 4) + kq;
                #pragma unroll
                for (int u = 0; u < 4; ++u) {
                    const int ii = c8 * 4 + u;
                    const float4 e4 = epc[u * 64];                  // 4 k's of one row
                    const float4 va = vp[ii * 8];                   // V[row][0..3]
                    const float4 vb = vp[ii * 8 + 1];               // V[row][4..7]
                    rp0[0] += e4.x * va.x; rp0[1] += e4.x * va.y; rp0[2] += e4.x * va.z; rp0[3] += e4.x * va.w;
                    rp0[4] += e4.x * vb.x; rp0[5] += e4.x * vb.y; rp0[6] += e4.x * vb.z; rp0[7] += e4.x * vb.w;
                    rp1[0] += e4.y * va.x; rp1[1] += e4.y * va.y; rp1[2] += e4.y * va.z; rp1[3] += e4.y * va.w;
                    rp1[4] += e4.y * vb.x; rp1[5] += e4.y * vb.y; rp1[6] += e4.y * vb.z; rp1[7] += e4.y * vb.w;
                    rp2[0] += e4.z * va.x; rp2[1] += e4.z * va.y; rp2[2] += e4.z * va.z; rp2[3] += e4.z * va.w;
                    rp2[4] += e4.z * vb.x; rp2[5] += e4.z * vb.y; rp2[6] += e4.z * vb.z; rp2[7] += e4.z * vb.w;
                    rp3[0] += e4.w * va.x; rp3[1] += e4.w * va.y; rp3[2] += e4.w * va.z; rp3[3] += e4.w * va.w;
                    rp3[4] += e4.w * vb.x; rp3[5] += e4.w * vb.y; rp3[6] += e4.w * vb.z; rp3[7] += e4.w * vb.w;
                }
            }
            // reduce across the 4 sub-groups (rows) -> all lanes hold wave totals
            #pragma unroll
            for (int j = 0; j < BS; ++j) {
                float a0 = rp0[j]; a0 += __shfl_xor(a0, 16, 64); a0 += __shfl_xor(a0, 32, 64); rp0[j] = a0;
                float a1 = rp1[j]; a1 += __shfl_xor(a1, 16, 64); a1 += __shfl_xor(a1, 32, 64); rp1[j] = a1;
                float a2 = rp2[j]; a2 += __shfl_xor(a2, 16, 64); a2 += __shfl_xor(a2, 32, 64); rp2[j] = a2;
                float a3 = rp3[j]; a3 += __shfl_xor(a3, 16, 64); a3 += __shfl_xor(a3, 32, 64); rp3[j] = a3;
            }
            // lane writes slice c == sub of k = 4*kq + sub
            float w[BS];
            #pragma unroll
            for (int j = 0; j < BS; ++j) {
                const float t01 = (sub & 1) ? rp1[j] : rp0[j];
                const float t23 = (sub & 1) ? rp3[j] : rp2[j];
                w[j] = (sub & 2) ? t23 : t01;
            }
            float* dst = &Rpart[wv][4 * kq + sub][0];
            *reinterpret_cast<float4*>(dst)     = make_float4(w[0], w[1], w[2], w[3]);
            *reinterpret_cast<float4*>(dst + 4) = make_float4(w[4], w[5], w[6], w[7]);
        }
        __syncthreads();                                   // bar 4

        if (t < NY * BS) {
            const int k = t >> 3, j = t & 7;
            float ssum = 0.f;
            #pragma unroll
            for (int w = 0; w < NWAVE; ++w) ssum += Rpart[w][k][j];
            Rr[k][j] = ssum;
        } else if (t < NY * BS + 32) {
            scal[t - NY * BS] = 0.0f;                      // reset for next iter
        } else if (t < NY * BS + 32 + BS) {
            umaxI[t - NY * BS - 32] = 0;
        }
        __syncthreads();                                   // bar 5

        // ---- Phase D: per-scenario update + simplex projection (wave j) ----
        if (wv < BS) {
            const int j = wv, k = lane;
            const float r = Rr[k][j];
            const float gz = 2.0f * r - yhReg;
            const float vz = zReg - lr * gz;

            // bitonic sort (descending) across 64 lanes
            float sv = vz;
            #pragma unroll
            for (int sz = 2; sz <= 64; sz <<= 1) {
                #pragma unroll
                for (int st = sz >> 1; st > 0; st >>= 1) {
                    const float other = __shfl_xor(sv, st, 64);
                    const bool desc = ((lane & sz) == 0);
                    const bool lower = ((lane & st) == 0);
                    const float mx = fmaxf(sv, other), mn = fminf(sv, other);
                    sv = (lower == desc) ? mx : mn;
                }
            }
            // inclusive scan -> cumsum - 1
            float css = sv;
            #pragma unroll
            for (int off = 1; off < 64; off <<= 1) {
                const float nb = __shfl_up(css, off, 64);
                if (lane >= off) css += nb;
            }
            css -= 1.0f;
            const bool cond = (sv - css / (float)(lane + 1)) > 0.0f;
            const unsigned long long bal = __ballot(cond);
            const int idx = __popcll(bal) - 1;
            const float cssIdx = __shfl(css, idx, 64);
            const float theta = cssIdx / (float)(idx + 1);
            zReg = fmaxf(vz - theta, 0.0f);
            Zs[j][k] = zReg;
            if (lane == 0) {
                cS[j] = cS[j] - lr * gcS[j];
                lamS[j] = fmaxf(lamS[j] - lr * glamS[j], 0.0f);
            }
        }
        __syncthreads();                                   // bar 6
    }

    if (wv < BS) zout[(sc0 + wv) * NY + lane] = zReg;
}

extern "C" void kernel_launch(void* const* d_in, const int* in_sizes, int n_in,
                              void* d_out, int out_size, void* d_ws, size_t ws_size,
                              hipStream_t stream) {
    const float* X   = (const float*)d_in[0];
    const float* Y   = (const float*)d_in[1];
    const float* rho = (const float*)d_in[2];
    const float* W   = (const float*)d_in[3];
    const float* b   = (const float*)d_in[4];

    float* out   = (float*)d_out;
    float* zout  = out;                 // Z_star: 2048*64
    float* yhat  = out + NOBS * NY;     // Y_hat:  2048*64
    float* ep    = (float*)d_ws;        // 2048*64 f32 = 512 KB
    float* epsum = ep + NOBS * NY;      // 1 f32

    hipMemsetAsync(epsum, 0, sizeof(float), stream);
    prep_kernel<<<NOBS / 4, 256, 0, stream>>>(X, Y, W, b, yhat, ep, epsum);
    solve_kernel<<<NOBS / BS, NT, 0, stream>>>(ep, yhat, epsum, rho, zout);
}

// Round 3
// 2606.323 us; speedup vs baseline: 2.1743x; 2.1743x over previous
//
#include <hip/hip_runtime.h>

#define NOBS 2048
#define NX   128
#define NY   64
#define BS   8            // scenarios per solver block
#define NT   1024         // solver block threads (16 waves)
#define NWAVE (NT / 64)
#define NITER 64
#define VSTRIDE 12        // V row stride in floats: 48B keeps float4 align, 8-row bank period

// ---- DPP wave reductions (VALU pipe, keeps LDS pipe free) ----
template <int CTRL>
__device__ __forceinline__ float dpp_f(float x) {
    return __int_as_float(__builtin_amdgcn_update_dpp(
        0, __float_as_int(x), CTRL, 0xf, 0xf, true));  // bound_ctrl: invalid lanes read 0
}
// After these, lane 63 holds the full-wave result.
__device__ __forceinline__ float wave_sum64(float v) {
    v += dpp_f<0x111>(v);   // row_shr:1
    v += dpp_f<0x112>(v);   // row_shr:2
    v += dpp_f<0x114>(v);   // row_shr:4
    v += dpp_f<0x118>(v);   // row_shr:8  -> lane 16r+15 = row sum
    v += dpp_f<0x142>(v);   // row_bcast15
    v += dpp_f<0x143>(v);   // row_bcast31 -> lane 63 = total
    return v;
}
__device__ __forceinline__ float wave_max64_nonneg(float v) {  // requires v >= 0
    v = fmaxf(v, dpp_f<0x111>(v));
    v = fmaxf(v, dpp_f<0x112>(v));
    v = fmaxf(v, dpp_f<0x114>(v));
    v = fmaxf(v, dpp_f<0x118>(v));
    v = fmaxf(v, dpp_f<0x142>(v));
    v = fmaxf(v, dpp_f<0x143>(v));
    return v;
}
__device__ __forceinline__ float rl(float v, int k) {
    return __int_as_float(__builtin_amdgcn_readlane(__float_as_int(v), k));
}

// ---- Kernel 1: Y_hat = X@W^T + b ; ep = Y - Y_hat ; epsum = sum(ep) ----
__global__ __launch_bounds__(256) void prep_kernel(
    const float* __restrict__ X, const float* __restrict__ Y,
    const float* __restrict__ W, const float* __restrict__ b,
    float* __restrict__ yhat_out, float* __restrict__ ep, float* __restrict__ epsum)
{
    __shared__ float Xs[4][NX];
    const int t = threadIdx.x;
    const int row0 = blockIdx.x * 4;
    for (int f = t; f < 4 * NX; f += 256)
        Xs[f >> 7][f & 127] = X[(row0 + (f >> 7)) * NX + (f & 127)];
    __syncthreads();

    const int k = t & 63;
    const int r = t >> 6;
    const float4* W4 = reinterpret_cast<const float4*>(W + k * NX);
    const float4* X4 = reinterpret_cast<const float4*>(&Xs[r][0]);
    float acc = 0.f;
    #pragma unroll
    for (int x = 0; x < NX / 4; ++x) {
        float4 wv = W4[x];
        float4 xv = X4[x];
        acc += wv.x * xv.x + wv.y * xv.y + wv.z * xv.z + wv.w * xv.w;
    }
    const float yh = acc + b[k];
    const int i = row0 + r;
    yhat_out[i * NY + k] = yh;
    const float e = Y[i * NY + k] - yh;
    ep[i * NY + k] = e;

    float se = wave_sum64(e);
    if ((t & 63) == 63) atomicAdd(epsum, se);
}

// ---- Kernel 2: batched projected-subgradient DRO solve ----
__global__ __launch_bounds__(NT) void solve_kernel(
    const float* __restrict__ ep, const float* __restrict__ yhat,
    const float* __restrict__ epsum, const float* __restrict__ rho_p,
    float* __restrict__ zout)
{
    __shared__ float Vf[NOBS * VSTRIDE];    // 96 KB  weighted residual v, stride-12 rows
    __shared__ float Rpart[NWAVE][BS][NY];  // 32 KB  per-wave partial r (j-major, b32 access)
    __shared__ float Rr[BS][NY];            // 2 KB   r = ep^T v
    __shared__ float Zs[BS][NY];            // 2 KB   z (lane k of each wave caches Zs[j][k])
    __shared__ float scal[32];              // [a | eq | a*s | eq*s] x 8 scenarios
    __shared__ int   umaxI[BS];             // float bits of umax (u >= 0)
    __shared__ float cS[BS], lamS[BS], gcS[BS], glamS[BS];

    const int t = threadIdx.x;
    const int lane = t & 63;
    const int wv = t >> 6;
    const int sc0 = blockIdx.x * BS;
    const float rho = rho_p[0];

    // persistent per-wave registers (waves 0..7 own scenario j = wv)
    float zReg = 1.0f / 64.0f;
    float yhReg = 0.0f;
    if (wv < BS) yhReg = yhat[(sc0 + wv) * NY + lane];

    if (t < BS * NY) Zs[t >> 6][t & 63] = 1.0f / 64.0f;
    if (t < 32) scal[t] = 0.0f;
    if (t < BS) {
        umaxI[t] = 0;
        cS[t] = epsum[0] * (1.0f / 131072.0f);  // mean(ep) == mean(ep @ z0)
        lamS[t] = 1.0f;
    }
    __syncthreads();

    const int i0 = t;          // Phase A/B4: thread owns obs rows t and t+1024
    const int i1 = t + NT;
    const float4* ep4 = reinterpret_cast<const float4*>(ep);
    const float4* epA = ep4 + i0 * (NY / 4);
    const float4* epB = ep4 + i1 * (NY / 4);

    for (int it = 0; it < NITER; ++it) {
        const float lr = 0.05f / sqrtf((float)it + 1.0f);

        // ==== Phases A..B4: s, stats, v (stats regs scoped => dead before Phase C) ====
        {
            // ---- Phase A: s = ep.z - c; Z broadcast via readlane (no LDS in k-loop) ----
            float zc[BS];
            #pragma unroll
            for (int j = 0; j < BS; ++j) zc[j] = Zs[j][lane];   // lane k holds Z[j][k]

            float s0[BS], s1[BS];
            #pragma unroll
            for (int j = 0; j < BS; ++j) { s0[j] = 0.f; s1[j] = 0.f; }

            #pragma unroll 4
            for (int k4 = 0; k4 < NY / 4; ++k4) {
                const float4 ea = epA[k4];
                const float4 eb = epB[k4];
                const float eaf[4] = {ea.x, ea.y, ea.z, ea.w};
                const float ebf[4] = {eb.x, eb.y, eb.z, eb.w};
                #pragma unroll
                for (int c = 0; c < 4; ++c) {
                    const int k = 4 * k4 + c;     // wave-uniform lane index
                    #pragma unroll
                    for (int j = 0; j < BS; ++j) {
                        const float zk = rl(zc[j], k);   // SGPR broadcast
                        s0[j] += eaf[c] * zk;
                        s1[j] += ebf[c] * zk;
                    }
                }
            }
            float lamR[BS];
            #pragma unroll
            for (int j = 0; j < BS; ++j) {
                const float cj = cS[j];
                lamR[j] = lamS[j];
                s0[j] -= cj; s1[j] -= cj;
            }

            // ---- B1: umax per scenario via DPP max + LDS atomic max (bits, u>=0) ----
            #pragma unroll
            for (int j = 0; j < BS; ++j) {
                float pm = fmaxf(s0[j] * s0[j], s1[j] * s1[j]);
                pm = wave_max64_nonneg(pm);
                if (lane == 63) atomicMax(&umaxI[j], __float_as_int(pm));
            }
            __syncthreads();                                   // bar 1

            float um[BS];
            #pragma unroll
            for (int j = 0; j < BS; ++j) um[j] = __int_as_float(umaxI[j]);

            // ---- B2: sums of a, eq, a*s, eq*s (JAX balanced-tie semantics) ----
            #pragma unroll
            for (int j = 0; j < BS; ++j) {
                const float umj = um[j], lm = lamR[j];
                float pa, pe, pas, pes;
                {
                    const float s = s0[j], u = s * s;
                    const float x = (u - umj) + lm;
                    const float a = (x > -lm) ? 1.0f : ((x == -lm) ? 0.5f : 0.0f);
                    const float e = (u == umj) ? 1.0f : 0.0f;
                    pa = a; pe = e; pas = a * s; pes = e * s;
                }
                {
                    const float s = s1[j], u = s * s;
                    const float x = (u - umj) + lm;
                    const float a = (x > -lm) ? 1.0f : ((x == -lm) ? 0.5f : 0.0f);
                    const float e = (u == umj) ? 1.0f : 0.0f;
                    pa += a; pe += e; pas += a * s; pes += e * s;
                }
                pa = wave_sum64(pa); pe = wave_sum64(pe);
                pas = wave_sum64(pas); pes = wave_sum64(pes);
                if (lane == 63) {
                    atomicAdd(&scal[j], pa);       atomicAdd(&scal[8 + j], pe);
                    atomicAdd(&scal[16 + j], pas); atomicAdd(&scal[24 + j], pes);
                }
            }
            __syncthreads();                                   // bar 2

            // ---- B4: wA inline; v = (a/n + eq*wA) * s into Vf ----
            if (t < BS) {   // finalize gc/glam while others build v
                const float abar = scal[t] * (1.0f / (float)NOBS);
                const float wAt = (1.0f - abar) / scal[8 + t];
                gcS[t] = -2.0f * (scal[16 + t] * (1.0f / (float)NOBS) + wAt * scal[24 + t]);
                glamS[t] = (rho - 2.0f) + 2.0f * abar;
            }
            float v0[BS], v1[BS];
            #pragma unroll
            for (int j = 0; j < BS; ++j) {
                const float abar = scal[j] * (1.0f / (float)NOBS);
                const float wAj = (1.0f - abar) / scal[8 + j];
                const float umj = um[j], lm = lamR[j];
                {
                    const float s = s0[j], u = s * s;
                    const float x = (u - umj) + lm;
                    const float a = (x > -lm) ? 1.0f : ((x == -lm) ? 0.5f : 0.0f);
                    const float e = (u == umj) ? 1.0f : 0.0f;
                    v0[j] = (a * (1.0f / (float)NOBS) + e * wAj) * s;
                }
                {
                    const float s = s1[j], u = s * s;
                    const float x = (u - umj) + lm;
                    const float a = (x > -lm) ? 1.0f : ((x == -lm) ? 0.5f : 0.0f);
                    const float e = (u == umj) ? 1.0f : 0.0f;
                    v1[j] = (a * (1.0f / (float)NOBS) + e * wAj) * s;
                }
            }
            *reinterpret_cast<float4*>(&Vf[i0 * VSTRIDE])     = make_float4(v0[0], v0[1], v0[2], v0[3]);
            *reinterpret_cast<float4*>(&Vf[i0 * VSTRIDE + 4]) = make_float4(v0[4], v0[5], v0[6], v0[7]);
            *reinterpret_cast<float4*>(&Vf[i1 * VSTRIDE])     = make_float4(v1[0], v1[1], v1[2], v1[3]);
            *reinterpret_cast<float4*>(&Vf[i1 * VSTRIDE + 4]) = make_float4(v1[4], v1[5], v1[6], v1[7]);
        }
        __syncthreads();                                   // bar 3

        // ---- Phase C: r = ep^T v, 4 consecutive rows per step ----
        {
            const int sub = lane >> 4;        // row within quad
            const int kq  = lane & 15;        // k-quad: k = 4*kq + c
            float rp0[BS], rp1[BS], rp2[BS], rp3[BS];   // rp_c[j], c = k offset
            #pragma unroll
            for (int j = 0; j < BS; ++j) { rp0[j] = 0.f; rp1[j] = 0.f; rp2[j] = 0.f; rp3[j] = 0.f; }

            const int rb = wv * (NOBS / NWAVE);
            #pragma unroll 2
            for (int c8 = 0; c8 < 8; ++c8) {
                #pragma unroll
                for (int u = 0; u < 4; ++u) {
                    const int row = rb + c8 * 16 + u * 4 + sub;
                    const float4 e4 = ep4[row * (NY / 4) + kq];   // wave: 1KB contiguous
                    const float4 va = *reinterpret_cast<const float4*>(&Vf[row * VSTRIDE]);
                    const float4 vb = *reinterpret_cast<const float4*>(&Vf[row * VSTRIDE + 4]);
                    rp0[0] += e4.x * va.x; rp0[1] += e4.x * va.y; rp0[2] += e4.x * va.z; rp0[3] += e4.x * va.w;
                    rp0[4] += e4.x * vb.x; rp0[5] += e4.x * vb.y; rp0[6] += e4.x * vb.z; rp0[7] += e4.x * vb.w;
                    rp1[0] += e4.y * va.x; rp1[1] += e4.y * va.y; rp1[2] += e4.y * va.z; rp1[3] += e4.y * va.w;
                    rp1[4] += e4.y * vb.x; rp1[5] += e4.y * vb.y; rp1[6] += e4.y * vb.z; rp1[7] += e4.y * vb.w;
                    rp2[0] += e4.z * va.x; rp2[1] += e4.z * va.y; rp2[2] += e4.z * va.z; rp2[3] += e4.z * va.w;
                    rp2[4] += e4.z * vb.x; rp2[5] += e4.z * vb.y; rp2[6] += e4.z * vb.z; rp2[7] += e4.z * vb.w;
                    rp3[0] += e4.w * va.x; rp3[1] += e4.w * va.y; rp3[2] += e4.w * va.z; rp3[3] += e4.w * va.w;
                    rp3[4] += e4.w * vb.x; rp3[5] += e4.w * vb.y; rp3[6] += e4.w * vb.z; rp3[7] += e4.w * vb.w;
                }
            }
            // reduce across the 4 sub-groups; then lane keeps slice c == sub
            #pragma unroll
            for (int j = 0; j < BS; ++j) {
                float a0 = rp0[j]; a0 += __shfl_xor(a0, 16); a0 += __shfl_xor(a0, 32);
                float a1 = rp1[j]; a1 += __shfl_xor(a1, 16); a1 += __shfl_xor(a1, 32);
                float a2 = rp2[j]; a2 += __shfl_xor(a2, 16); a2 += __shfl_xor(a2, 32);
                float a3 = rp3[j]; a3 += __shfl_xor(a3, 16); a3 += __shfl_xor(a3, 32);
                const float t01 = (sub & 1) ? a1 : a0;
                const float t23 = (sub & 1) ? a3 : a2;
                Rpart[wv][j][4 * kq + sub] = (sub & 2) ? t23 : t01;   // b32, conflict-free
            }
        }
        __syncthreads();                                   // bar 4

        if (t < BS * NY) {
            const int j = t >> 6, k = t & 63;
            float ssum = 0.f;
            #pragma unroll
            for (int w = 0; w < NWAVE; ++w) ssum += Rpart[w][j][k];
            Rr[j][k] = ssum;
        } else if (t < BS * NY + 32) {
            scal[t - BS * NY] = 0.0f;                      // reset for next iter
        } else if (t < BS * NY + 32 + BS) {
            umaxI[t - BS * NY - 32] = 0;
        }
        __syncthreads();                                   // bar 5

        // ---- Phase D: per-scenario update + simplex projection (wave j) ----
        if (wv < BS) {
            const int j = wv, k = lane;
            const float r = Rr[j][k];
            const float gz = 2.0f * r - yhReg;
            const float vz = zReg - lr * gz;

            // bitonic sort (descending) across 64 lanes
            float sv = vz;
            #pragma unroll
            for (int sz = 2; sz <= 64; sz <<= 1) {
                #pragma unroll
                for (int st = sz >> 1; st > 0; st >>= 1) {
                    const float other = __shfl_xor(sv, st, 64);
                    const bool desc = ((lane & sz) == 0);
                    const bool lower = ((lane & st) == 0);
                    const float mx = fmaxf(sv, other), mn = fminf(sv, other);
                    sv = (lower == desc) ? mx : mn;
                }
            }
            // inclusive scan -> cumsum - 1
            float css = sv;
            #pragma unroll
            for (int off = 1; off < 64; off <<= 1) {
                const float nb = __shfl_up(css, off, 64);
                if (lane >= off) css += nb;
            }
            css -= 1.0f;
            const bool cond = (sv - css / (float)(lane + 1)) > 0.0f;
            const unsigned long long bal = __ballot(cond);
            const int idx = __popcll(bal) - 1;
            const float cssIdx = __shfl(css, idx, 64);
            const float theta = cssIdx / (float)(idx + 1);
            zReg = fmaxf(vz - theta, 0.0f);
            Zs[j][k] = zReg;
            if (lane == 0) {
                cS[j] = cS[j] - lr * gcS[j];
                lamS[j] = fmaxf(lamS[j] - lr * glamS[j], 0.0f);
            }
        }
        __syncthreads();                                   // bar 6
    }

    if (wv < BS) zout[(sc0 + wv) * NY + lane] = zReg;
}

extern "C" void kernel_launch(void* const* d_in, const int* in_sizes, int n_in,
                              void* d_out, int out_size, void* d_ws, size_t ws_size,
                              hipStream_t stream) {
    const float* X   = (const float*)d_in[0];
    const float* Y   = (const float*)d_in[1];
    const float* rho = (const float*)d_in[2];
    const float* W   = (const float*)d_in[3];
    const float* b   = (const float*)d_in[4];

    float* out   = (float*)d_out;
    float* zout  = out;                 // Z_star: 2048*64
    float* yhat  = out + NOBS * NY;     // Y_hat:  2048*64
    float* ep    = (float*)d_ws;        // 2048*64 f32 = 512 KB
    float* epsum = ep + NOBS * NY;      // 1 f32

    hipMemsetAsync(epsum, 0, sizeof(float), stream);
    prep_kernel<<<NOBS / 4, 256, 0, stream>>>(X, Y, W, b, yhat, ep, epsum);
    solve_kernel<<<NOBS / BS, NT, 0, stream>>>(ep, yhat, epsum, rho, zout);
}